// Round 4
// baseline (179.494 us; speedup 1.0000x reference)
//
#include <hip/hip_runtime.h>
#include <hip/hip_bf16.h>
#include <stdint.h>

#define ALPHA_LO 0.8187307530779818f
#define ALPHA_HI 0.9607894391523232f

#define BATCH 64
#define TT    2000
#define II    512
#define HH    512
#define MM    (BATCH*TT)
#define LCH   50
#define CCH   (TT/LCH)

typedef __bf16 bf16;
typedef bf16  bf16x8 __attribute__((ext_vector_type(8)));
typedef float f32x4  __attribute__((ext_vector_type(4)));

#define GLDS(src, dst) __builtin_amdgcn_global_load_lds( \
    (const __attribute__((address_space(1))) unsigned int*)(src), \
    (__attribute__((address_space(3))) unsigned int*)(dst), 16, 0, 0)

// ---------------- K0: convert + transpose W -> fragment-ordered bf16 image --
// Wbt[ks:16][jj:32][kq:4][fr:16][e:8]  = W[jj*16+fr][ks*32+kq*8+e]
// Per k-step the 32 KB chunk is the exact LDS image; every wave-level LDS
// access (glds write, ds_read_b128 frag read) is contiguous -> 0 conflicts.
__global__ void k_convW(const float* __restrict__ W, bf16* __restrict__ Wbt) {
    const int t  = blockIdx.x * 256 + threadIdx.x;   // 0..32767
    const int h  = t >> 6;                           // 0..511 (W row = col of B)
    const int kb = t & 63;                           // 8-float k group
    const float* src = W + (size_t)h * II + kb * 8;
    float4 v0 = *(const float4*)(src);
    float4 v1 = *(const float4*)(src + 4);
    bf16x8 o;
    o[0]=(bf16)v0.x; o[1]=(bf16)v0.y; o[2]=(bf16)v0.z; o[3]=(bf16)v0.w;
    o[4]=(bf16)v1.x; o[5]=(bf16)v1.y; o[6]=(bf16)v1.z; o[7]=(bf16)v1.w;
    const int ks = kb >> 2, kq = kb & 3, jj = h >> 4, fr = h & 15;
    bf16* dst = Wbt + (size_t)ks * 16384 + jj * 512 + kq * 128 + fr * 8;
    *(bf16x8*)dst = o;
}

// ---------------- K1: GEMM  Y[M,H] = X[M,I] * W[H,I]^T  (bf16 MFMA) --------
// block 128x512 (full N), 8 waves (2m x 4n), wave tile 64x128, BK=32.
// LDS fragment-ordered: Al[buf][blk:8][kq:4][fr:16][8], Bl[buf][jj:32][kq][fr][8]
// -> every ds op is wave-contiguous 1KB. Depth-2 prefetch, B issued before A
// so the compiler's auto vmcnt(12) for A regs also guarantees B landed; no
// vmcnt(0) drain; one raw s_barrier per K-step.
__global__ __launch_bounds__(512, 2) void k_gemm(const float* __restrict__ X,
                                                 const bf16* __restrict__ Wbt,
                                                 bf16* __restrict__ Y) {
    __shared__ bf16 Al[2][4096];    // 2 x 8 KB
    __shared__ bf16 Bl[4][16384];   // 4 x 32 KB
    const int tid  = threadIdx.x;
    const int m0   = blockIdx.x * 128;
    const int lane = tid & 63;
    const int wv   = tid >> 6;
    const int wr   = (wv >> 2) * 64;     // wave row base
    const int wcj  = (wv & 3) * 8;       // wave col-tile (jj) base
    const int wblk = (wv >> 2) * 4;      // A blk base
    const int fr   = lane & 15;
    const int kq   = lane >> 4;

    f32x4 acc[4][8] = {};

    // A staging: thread t writes LDS byte t*16 (contiguous per wave)
    const int arow = ((tid >> 6) << 4) + (tid & 15);   // 0..127
    const int akq  = (tid >> 4) & 3;
    const float* xa = X + (size_t)(m0 + arow) * II + akq * 8;
    const int aoff = tid * 8;                          // element offset in Al

    // B staging: identity copy; src per-lane, dst wave-uniform + lane*16
    const bf16* wsrc = Wbt + wv * 512 + lane * 8;

    float4 av[3][2];

    // prologue: B(0), A(0), B(1), A(1)  (B before A at equal depth)
    #pragma unroll
    for (int q = 0; q < 4; ++q) GLDS(wsrc + q * 4096,         &Bl[0][(q * 8 + wv) * 512]);
    av[0][0] = *(const float4*)(xa);
    av[0][1] = *(const float4*)(xa + 4);
    #pragma unroll
    for (int q = 0; q < 4; ++q) GLDS(wsrc + 16384 + q * 4096, &Bl[1][(q * 8 + wv) * 512]);
    av[1][0] = *(const float4*)(xa + 32);
    av[1][1] = *(const float4*)(xa + 36);

    #pragma unroll
    for (int ks = 0; ks < 16; ++ks) {
        const int bcur = ks & 3;
        const int acur = ks & 1;
        const int rcur = ks % 3;
        // depth-2 prefetch issue (B first, then A)
        if (ks + 2 < 16) {
            #pragma unroll
            for (int q = 0; q < 4; ++q)
                GLDS(wsrc + (size_t)(ks + 2) * 16384 + q * 4096,
                     &Bl[(ks + 2) & 3][(q * 8 + wv) * 512]);
            av[(ks + 2) % 3][0] = *(const float4*)(xa + (size_t)(ks + 2) * 32);
            av[(ks + 2) % 3][1] = *(const float4*)(xa + (size_t)(ks + 2) * 32 + 4);
        }
        // cvt + stage A(ks); auto vmcnt here also guarantees B(ks) landed
        float4 a0 = av[rcur][0], a1 = av[rcur][1];
        bf16x8 c;
        c[0]=(bf16)a0.x; c[1]=(bf16)a0.y; c[2]=(bf16)a0.z; c[3]=(bf16)a0.w;
        c[4]=(bf16)a1.x; c[5]=(bf16)a1.y; c[6]=(bf16)a1.z; c[7]=(bf16)a1.w;
        *(bf16x8*)(&Al[acur][aoff]) = c;
        asm volatile("s_waitcnt lgkmcnt(0)" ::: "memory");
        __builtin_amdgcn_s_barrier();
        // fragment reads: all wave-contiguous 1KB -> conflict-free
        bf16x8 af[4], bb[8];
        #pragma unroll
        for (int i = 0; i < 4; ++i)
            af[i] = *(const bf16x8*)(&Al[acur][(wblk + i) * 512 + lane * 8]);
        #pragma unroll
        for (int j = 0; j < 8; ++j)
            bb[j] = *(const bf16x8*)(&Bl[bcur][(wcj + j) * 512 + lane * 8]);
        __builtin_amdgcn_s_setprio(1);
        #pragma unroll
        for (int i = 0; i < 4; ++i)
            #pragma unroll
            for (int j = 0; j < 8; ++j)
                acc[i][j] = __builtin_amdgcn_mfma_f32_16x16x32_bf16(af[i], bb[j], acc[i][j], 0, 0, 0);
        __builtin_amdgcn_s_setprio(0);
        asm volatile("" ::: "memory");
    }

    // epilogue: C row = (lane>>4)*4 + r, col = lane&15
    #pragma unroll
    for (int i = 0; i < 4; ++i)
        #pragma unroll
        for (int j = 0; j < 8; ++j) {
            const int row = m0 + wr + i * 16 + kq * 4;
            const int col = (wcj + j) * 16 + fr;
            #pragma unroll
            for (int r = 0; r < 4; ++r)
                Y[(size_t)(row + r) * HH + col] = (bf16)acc[i][j][r];
        }
}

// ---------------- K2: per-chunk Horner partial ------------------------------
__global__ void k_chunk(const bf16* __restrict__ Y, const float* __restrict__ alpha,
                        float* __restrict__ P) {
    const int c = blockIdx.x, b = blockIdx.y;
    const int lane = threadIdx.x;
    const int h0 = lane * 8;
    float a[8], p[8];
    #pragma unroll
    for (int k = 0; k < 8; ++k) {
        a[k] = fminf(fmaxf(alpha[h0 + k], ALPHA_LO), ALPHA_HI);
        p[k] = 0.f;
    }
    const bf16* base = Y + ((size_t)b * TT + (size_t)c * LCH) * HH + h0;
    for (int j = 0; j < LCH; ++j) {
        bf16x8 w = *(const bf16x8*)(base + (size_t)j * HH);
        #pragma unroll
        for (int k = 0; k < 8; ++k) p[k] = a[k] * p[k] + (float)w[k];
    }
    float* po = P + ((size_t)c * BATCH + b) * HH + h0;
    #pragma unroll
    for (int k = 0; k < 8; ++k) po[k] = (1.f - a[k]) * p[k];
}

// ---------------- K3: sequential prefix over chunks -------------------------
__global__ void k_prefix(const float* __restrict__ alpha, const float* __restrict__ u0,
                         const float* __restrict__ P, float* __restrict__ V) {
    const int g = blockIdx.x * 256 + threadIdx.x;
    const int h = g & (HH - 1);
    float a = fminf(fmaxf(alpha[h], ALPHA_LO), ALPHA_HI);
    float a2 = a * a, a4 = a2 * a2, a5 = a4 * a;
    float b2 = a5 * a5, b4 = b2 * b2, a25 = b4 * a5;
    float aL = a25 * a25;
    float v = u0[g];
    for (int c = 0; c < CCH; ++c) {
        const size_t idx = (size_t)c * (BATCH * HH) + g;
        V[idx] = v;
        v = aL * v + P[idx];
    }
}

// ---------------- K4: per-chunk softmax accumulate --------------------------
__global__ void k_soft(const bf16* __restrict__ Y, const float* __restrict__ alpha,
                       const float* __restrict__ V, float* __restrict__ OutP) {
    const int c = blockIdx.x, b = blockIdx.y;
    const int lane = threadIdx.x;
    const int h0 = lane * 8;
    float a[8], bt[8], u[8], o[8];
    #pragma unroll
    for (int k = 0; k < 8; ++k) {
        a[k]  = fminf(fmaxf(alpha[h0 + k], ALPHA_LO), ALPHA_HI);
        bt[k] = 1.f - a[k];
        o[k]  = 0.f;
    }
    const float* vb = V + ((size_t)c * BATCH + b) * HH + h0;
    #pragma unroll
    for (int k = 0; k < 8; ++k) u[k] = vb[k];
    const bf16* base = Y + ((size_t)b * TT + (size_t)c * LCH) * HH + h0;
    for (int j = 0; j < LCH; ++j) {
        bf16x8 w = *(const bf16x8*)(base + (size_t)j * HH);
        float e[8], s = 0.f;
        #pragma unroll
        for (int k = 0; k < 8; ++k) {
            u[k] = a[k] * u[k] + bt[k] * (float)w[k];
            e[k] = __expf(u[k]);
            s += e[k];
        }
        #pragma unroll
        for (int off = 32; off >= 1; off >>= 1) s += __shfl_xor(s, off, 64);
        const float inv = 1.f / s;
        #pragma unroll
        for (int k = 0; k < 8; ++k) o[k] += e[k] * inv;
    }
    float* po = OutP + ((size_t)c * BATCH + b) * HH + h0;
    #pragma unroll
    for (int k = 0; k < 8; ++k) po[k] = o[k];
}

// ---------------- K5: reduce chunk partials -> out --------------------------
__global__ void k_reduce(const float* __restrict__ OutP, float* __restrict__ out) {
    const int g = blockIdx.x * 256 + threadIdx.x;
    float s = 0.f;
    for (int c = 0; c < CCH; ++c) s += OutP[(size_t)c * (BATCH * HH) + g];
    out[g] = s;
}

extern "C" void kernel_launch(void* const* d_in, const int* in_sizes, int n_in,
                              void* d_out, int out_size, void* d_ws, size_t ws_size,
                              hipStream_t stream) {
    const float* x     = (const float*)d_in[0];
    const float* W     = (const float*)d_in[1];
    const float* alpha = (const float*)d_in[2];
    const float* u0    = (const float*)d_in[3];
    float* out = (float*)d_out;

    char* ws = (char*)d_ws;
    bf16* Wbt = (bf16*)ws;                                  //   0.5 MB
    bf16* Yx  = (bf16*)(ws + 524288);                       // 131.1 MB
    float* P  = (float*)(ws + 524288 + 131072000);
    float* V  = P + (size_t)CCH * BATCH * HH;
    float* OutP = V + (size_t)CCH * BATCH * HH;

    hipLaunchKernelGGL(k_convW,  dim3(128),          dim3(256), 0, stream, W, Wbt);
    hipLaunchKernelGGL(k_gemm,   dim3(MM / 128),     dim3(512), 0, stream, x, Wbt, Yx);
    hipLaunchKernelGGL(k_chunk,  dim3(CCH, BATCH),   dim3(64),  0, stream, Yx, alpha, P);
    hipLaunchKernelGGL(k_prefix, dim3(BATCH*HH/256), dim3(256), 0, stream, alpha, u0, P, V);
    hipLaunchKernelGGL(k_soft,   dim3(CCH, BATCH),   dim3(64),  0, stream, Yx, alpha, V, OutP);
    hipLaunchKernelGGL(k_reduce, dim3(BATCH*HH/256), dim3(256), 0, stream, OutP, out);
}